// Round 6
// baseline (2063.003 us; speedup 1.0000x reference)
//
#include <hip/hip_runtime.h>
#include <hip/hip_fp16.h>

#define N_NODES 50000
#define N_EDGES 800000
#define CH 128
#define OUT_CH 64
#define K_ORD 25
#define SLICE ((size_t)N_NODES * CH)     // elements per full T_k slice
#define HS ((size_t)N_NODES * 64)        // elements per channel-half slice

typedef __attribute__((ext_vector_type(8))) short s16x8;
typedef __attribute__((ext_vector_type(4))) float f32x4;
typedef __attribute__((ext_vector_type(4))) unsigned int u32x4;

union U4H8 { uint4 u; u32x4 v4; __half2 h2[4]; ushort us[8]; };

// ---------- CSR build ----------
__global__ void count_kernel(const int* __restrict__ ei, float* __restrict__ deg,
                             int* __restrict__ indeg, int E) {
    int e = blockIdx.x * blockDim.x + threadIdx.x;
    if (e >= E) return;
    int s = ei[e];
    int d = ei[E + e];
    atomicAdd(&deg[s], 1.0f);
    atomicAdd(&indeg[d], 1);
}

__global__ __launch_bounds__(256) void scan1_kernel(const int* __restrict__ indeg,
                                                    int* __restrict__ loc,
                                                    int* __restrict__ bsum, int n) {
    __shared__ int tmp[256];
    int tid = threadIdx.x;
    int i = blockIdx.x * 256 + tid;
    int v = (i < n) ? indeg[i] : 0;
    tmp[tid] = v;
    __syncthreads();
    for (int off = 1; off < 256; off <<= 1) {
        int t = (tid >= off) ? tmp[tid - off] : 0;
        __syncthreads();
        tmp[tid] += t;
        __syncthreads();
    }
    if (i < n) loc[i] = tmp[tid] - v;
    if (tid == 255) bsum[blockIdx.x] = tmp[255];
}

__global__ __launch_bounds__(256) void scan2_kernel(int* __restrict__ bsum, int nb) {
    __shared__ int tmp[256];
    int tid = threadIdx.x;
    int v = (tid < nb) ? bsum[tid] : 0;
    tmp[tid] = v;
    __syncthreads();
    for (int off = 1; off < 256; off <<= 1) {
        int t = (tid >= off) ? tmp[tid - off] : 0;
        __syncthreads();
        tmp[tid] += t;
        __syncthreads();
    }
    if (tid < nb) bsum[tid] = tmp[tid] - v;
    if (tid == 255) bsum[nb] = tmp[255];
}

__global__ __launch_bounds__(256) void scan3_kernel(const int* __restrict__ loc,
                                                    const int* __restrict__ bsum,
                                                    int* __restrict__ rowptr,
                                                    int* __restrict__ cursor, int n, int nb) {
    int i = blockIdx.x * 256 + threadIdx.x;
    if (i < n) {
        int r = loc[i] + bsum[i >> 8];
        rowptr[i] = r;
        cursor[i] = r;
    }
    if (i == n) rowptr[n] = bsum[nb];
}

__global__ void scatter_kernel(const int* __restrict__ ei, const float* __restrict__ deg,
                               int* __restrict__ cursor, int* __restrict__ col,
                               float* __restrict__ ew, int E) {
    int e = blockIdx.x * blockDim.x + threadIdx.x;
    if (e >= E) return;
    int s = ei[e];
    int d = ei[E + e];
    float ds = deg[s], dd = deg[d];
    float dis_s = ds > 0.f ? rsqrtf(ds) : 0.f;
    float dis_d = dd > 0.f ? rsqrtf(dd) : 0.f;
    int pos = atomicAdd(&cursor[d], 1);
    col[pos] = s;
    ew[pos] = -dis_s * dis_d;
}

// ---------- x (fp32 [N][128]) -> T0 fp16 half-layout [2][N][64] ----------
__global__ __launch_bounds__(256) void cvt_kernel(const float* __restrict__ in,
                                                  ushort* __restrict__ T0, int ng) {
    int i = blockIdx.x * 256 + threadIdx.x;   // one 8-ch granule per thread
    if (i >= ng) return;
    int r = i >> 4, gg = i & 15;
    int h = gg >> 3, sub = gg & 7;
    float4 a = ((const float4*)in)[2 * i];
    float4 b = ((const float4*)in)[2 * i + 1];
    U4H8 p;
    p.h2[0] = __float22half2_rn(make_float2(a.x, a.y));
    p.h2[1] = __float22half2_rn(make_float2(a.z, a.w));
    p.h2[2] = __float22half2_rn(make_float2(b.x, b.y));
    p.h2[3] = __float22half2_rn(make_float2(b.z, b.w));
    ((uint4*)(T0 + (size_t)h * HS))[(size_t)r * 8 + sub] = p.u;
}

// ---------- W prep: WT[k][n][c] = fp16(W[k][c][n]) ----------
__global__ __launch_bounds__(256) void wprep_kernel(const float* __restrict__ W,
                                                    ushort* __restrict__ WT) {
    int idx = blockIdx.x * 256 + threadIdx.x;   // (k, n, c4)
    if (idx >= K_ORD * 128 * 32) return;
    int c4 = idx & 31;
    int nrow = (idx >> 5) & 127;
    int k = idx >> 12;
    const float* Wk = W + (size_t)k * CH * CH;
    ushort o[4];
    #pragma unroll
    for (int j = 0; j < 4; ++j)
        o[j] = __half_as_ushort(__float2half_rn(Wk[(c4 * 4 + j) * CH + nrow]));
    *(ushort2*)(WT + (size_t)k * CH * CH + nrow * CH + c4 * 4)     = make_ushort2(o[0], o[1]);
    *(ushort2*)(WT + (size_t)k * CH * CH + nrow * CH + c4 * 4 + 2) = make_ushort2(o[2], o[3]);
}

// ---------- prop over one 64-ch half: tout = (mode ? 2*P(tin) - tprev : P(tin)) ----------
// one wave per node; 8 groups x 8 lanes; each group gathers one edge row (128 B)
__global__ __launch_bounds__(256) void prop_kernel(
    const ushort* __restrict__ tin, const ushort* __restrict__ tprev,
    ushort* __restrict__ tout, const int* __restrict__ rowptr,
    const int* __restrict__ col, const float* __restrict__ ew, int n, int mode) {
    int wid = blockIdx.x * 4 + (threadIdx.x >> 6);
    if (wid >= n) return;
    int lane = threadIdx.x & 63;
    int g = lane >> 3, sub = lane & 7;
    int beg = rowptr[wid], end = rowptr[wid + 1];
    float acc[8] = {0.f, 0.f, 0.f, 0.f, 0.f, 0.f, 0.f, 0.f};
    for (int e0 = beg; e0 < end; e0 += 64) {
        int ne = min(64, end - e0);
        int c = 0; float w = 0.f;
        if (lane < ne) {
            c = __builtin_nontemporal_load(col + e0 + lane);
            w = __builtin_nontemporal_load(ew + e0 + lane);
        }
        for (int j8 = 0; j8 < ne; j8 += 8) {
            int j = j8 + g;
            int cj = __shfl(c, j & 63);
            float wj = __shfl(w, j & 63);
            if (j >= ne) wj = 0.f;
            U4H8 v;
            v.u = ((const uint4*)(tin + (size_t)cj * 64))[sub];
            #pragma unroll
            for (int t = 0; t < 4; ++t) {
                float2 f = __half22float2(v.h2[t]);
                acc[2 * t]     = fmaf(wj, f.x, acc[2 * t]);
                acc[2 * t + 1] = fmaf(wj, f.y, acc[2 * t + 1]);
            }
        }
    }
    #pragma unroll
    for (int i = 0; i < 8; ++i) {
        acc[i] += __shfl_xor(acc[i], 8);
        acc[i] += __shfl_xor(acc[i], 16);
        acc[i] += __shfl_xor(acc[i], 32);
    }
    if (g == 0) {
        size_t base = (size_t)wid * 64 + sub * 8;
        float r[8];
        if (mode) {
            U4H8 pv;
            pv.v4 = __builtin_nontemporal_load((const u32x4*)(tprev + base));
            #pragma unroll
            for (int t = 0; t < 4; ++t) {
                float2 f = __half22float2(pv.h2[t]);
                r[2 * t]     = 2.f * acc[2 * t]     - f.x;
                r[2 * t + 1] = 2.f * acc[2 * t + 1] - f.y;
            }
        } else {
            #pragma unroll
            for (int i = 0; i < 8; ++i) r[i] = acc[i];
        }
        U4H8 p;
        p.h2[0] = __float22half2_rn(make_float2(r[0], r[1]));
        p.h2[1] = __float22half2_rn(make_float2(r[2], r[3]));
        p.h2[2] = __float22half2_rn(make_float2(r[4], r[5]));
        p.h2[3] = __float22half2_rn(make_float2(r[6], r[7]));
        __builtin_nontemporal_store(p.v4, (u32x4*)(tout + base));
    }
}

// ---------- GEMM: C[M,128] (beta? +=) Σ_ks T[ks] @ WT[wk0+ks], fp16 MFMA ----------
// T slices in half-layout: slice ks base = T + ks*kstride; half h at base + h*HS
__global__ __launch_bounds__(256) void gemm_kernel(
    const ushort* __restrict__ T, size_t kstride, const ushort* __restrict__ WT,
    float* __restrict__ C, int M, int wk0, int nk, int beta) {
    __shared__ ushort As[128 * 128];
    __shared__ ushort Ws[128 * 128];
    int tid = threadIdx.x;
    int row0 = blockIdx.x * 128;
    int wave = tid >> 6, lane = tid & 63;
    int wrow = wave * 32;
    int lr = lane & 15, kg = lane >> 4;

    f32x4 acc[2][8];
    #pragma unroll
    for (int a = 0; a < 2; ++a)
        #pragma unroll
        for (int c = 0; c < 8; ++c)
            acc[a][c] = (f32x4){0.f, 0.f, 0.f, 0.f};

    for (int ks = 0; ks < nk; ++ks) {
        const ushort* Ak = T + (size_t)ks * kstride;
        const ushort* Wk = WT + (size_t)(wk0 + ks) * (CH * CH);
        #pragma unroll
        for (int i = 0; i < 8; ++i) {
            int idx = tid + i * 256;
            int r = idx >> 4, gg = idx & 15;
            int h = gg >> 3, sub = gg & 7;
            uint4 v = make_uint4(0u, 0u, 0u, 0u);
            int gr = row0 + r;
            if (gr < M) v = ((const uint4*)(Ak + (size_t)h * HS + (size_t)gr * 64))[sub];
            int gs = gg ^ (r & 15);
            *(uint4*)(&As[r * 128 + gs * 8]) = v;
        }
        #pragma unroll
        for (int i = 0; i < 8; ++i) {
            int idx = tid + i * 256;
            int r = idx >> 4, gg = idx & 15;
            uint4 v = ((const uint4*)(Wk + (size_t)r * CH))[gg];
            int gs = gg ^ (r & 15);
            *(uint4*)(&Ws[r * 128 + gs * 8]) = v;
        }
        __syncthreads();

        #pragma unroll
        for (int kc = 0; kc < 4; ++kc) {
            int gbase = kc * 4 + kg;
            int gs = gbase ^ lr;
            s16x8 a0 = *(const s16x8*)(&As[(wrow + lr) * 128 + gs * 8]);
            s16x8 a1 = *(const s16x8*)(&As[(wrow + 16 + lr) * 128 + gs * 8]);
            #pragma unroll
            for (int c = 0; c < 8; ++c) {
                s16x8 bfr = *(const s16x8*)(&Ws[(c * 16 + lr) * 128 + gs * 8]);
                acc[0][c] = __builtin_amdgcn_mfma_f32_16x16x32_f16(a0, bfr, acc[0][c], 0, 0, 0);
                acc[1][c] = __builtin_amdgcn_mfma_f32_16x16x32_f16(a1, bfr, acc[1][c], 0, 0, 0);
            }
        }
        __syncthreads();
    }

    #pragma unroll
    for (int rf = 0; rf < 2; ++rf)
        #pragma unroll
        for (int c = 0; c < 8; ++c)
            #pragma unroll
            for (int j = 0; j < 4; ++j) {
                int gr = row0 + wrow + rf * 16 + kg * 4 + j;
                int gc = c * 16 + lr;
                if (gr < M) {
                    float v = acc[rf][c][j];
                    if (beta) v += C[(size_t)gr * 128 + gc];
                    C[(size_t)gr * 128 + gc] = v;
                }
            }
}

// ---------- head: MFMA over Wcat = [w_mu | w_ls], fused leaky+bias+normalize ----------
__global__ __launch_bounds__(256) void head_kernel(
    const float* __restrict__ acc_in, const float* __restrict__ b,
    const float* __restrict__ w_mu, const float* __restrict__ b_mu,
    const float* __restrict__ w_ls, const float* __restrict__ b_ls,
    float* __restrict__ out, int M) {
    __shared__ ushort Hs[128 * 128];
    __shared__ ushort Ws[128 * 128];
    __shared__ float s_b[128];
    int tid = threadIdx.x;
    int row0 = blockIdx.x * 128;
    if (tid < 128) s_b[tid] = b[tid];
    __syncthreads();

    #pragma unroll
    for (int i = 0; i < 16; ++i) {
        int idx = tid + i * 256;
        int r = idx >> 5, c4 = idx & 31;
        float4 v = make_float4(0.f, 0.f, 0.f, 0.f);
        int gr = row0 + r;
        if (gr < M) v = ((const float4*)(acc_in + (size_t)gr * CH))[c4];
        float hv[4] = { v.x, v.y, v.z, v.w };
        #pragma unroll
        for (int j = 0; j < 4; ++j) {
            float h = hv[j] + s_b[c4 * 4 + j];
            hv[j] = h > 0.f ? h : 0.01f * h;
        }
        __half2 p0 = __float22half2_rn(make_float2(hv[0], hv[1]));
        __half2 p1 = __float22half2_rn(make_float2(hv[2], hv[3]));
        int gg = c4 >> 1, hh = c4 & 1;
        int gs = gg ^ (r & 15);
        uint2 pk;
        pk.x = *(unsigned int*)&p0;
        pk.y = *(unsigned int*)&p1;
        *(uint2*)(&Hs[r * 128 + gs * 8 + hh * 4]) = pk;
    }
    #pragma unroll
    for (int i = 0; i < 16; ++i) {
        int idx = tid + i * 256;
        int k = idx >> 5, n4 = idx & 31;
        const float* src = (n4 < 16) ? w_mu : w_ls;
        float4 v = ((const float4*)src)[k * 16 + (n4 & 15)];
        int gk = k >> 3, kk = k & 7;
        float vv[4] = { v.x, v.y, v.z, v.w };
        #pragma unroll
        for (int j = 0; j < 4; ++j) {
            int nn = n4 * 4 + j;
            int gs = gk ^ (nn & 15);
            Ws[nn * 128 + gs * 8 + kk] = __half_as_ushort(__float2half_rn(vv[j]));
        }
    }
    __syncthreads();

    int wave = tid >> 6, lane = tid & 63;
    int wrow = wave * 32;
    int lr = lane & 15, kg = lane >> 4;
    f32x4 acc[2][8];
    #pragma unroll
    for (int a = 0; a < 2; ++a)
        #pragma unroll
        for (int c = 0; c < 8; ++c)
            acc[a][c] = (f32x4){0.f, 0.f, 0.f, 0.f};

    #pragma unroll
    for (int kc = 0; kc < 4; ++kc) {
        int gbase = kc * 4 + kg;
        int gs = gbase ^ lr;
        s16x8 a0 = *(const s16x8*)(&Hs[(wrow + lr) * 128 + gs * 8]);
        s16x8 a1 = *(const s16x8*)(&Hs[(wrow + 16 + lr) * 128 + gs * 8]);
        #pragma unroll
        for (int c = 0; c < 8; ++c) {
            s16x8 bfr = *(const s16x8*)(&Ws[(c * 16 + lr) * 128 + gs * 8]);
            acc[0][c] = __builtin_amdgcn_mfma_f32_16x16x32_f16(a0, bfr, acc[0][c], 0, 0, 0);
            acc[1][c] = __builtin_amdgcn_mfma_f32_16x16x32_f16(a1, bfr, acc[1][c], 0, 0, 0);
        }
    }

    #pragma unroll
    for (int rf = 0; rf < 2; ++rf)
        #pragma unroll
        for (int j = 0; j < 4; ++j) {
            int gr = row0 + wrow + rf * 16 + kg * 4 + j;
            float muv[4], lsv[4];
            float s2 = 0.f;
            #pragma unroll
            for (int c = 0; c < 4; ++c) {
                muv[c] = acc[rf][c][j] + b_mu[c * 16 + lr];
                float l = acc[rf][4 + c][j] + b_ls[c * 16 + lr];
                lsv[c] = l;
                s2 = fmaf(l, l, s2);
            }
            s2 += __shfl_xor(s2, 1);
            s2 += __shfl_xor(s2, 2);
            s2 += __shfl_xor(s2, 4);
            s2 += __shfl_xor(s2, 8);
            float sc = 1.8f / fmaxf(sqrtf(s2), 1e-12f);
            if (gr < M) {
                size_t base = (size_t)gr * OUT_CH;
                #pragma unroll
                for (int c = 0; c < 4; ++c) {
                    int gc = c * 16 + lr;
                    out[base + gc] = muv[c];
                    out[(size_t)N_NODES * OUT_CH + base + gc] = lsv[c] * sc;
                    out[2 * (size_t)N_NODES * OUT_CH + base + gc] = muv[c];
                }
            }
        }
}

// ---------- host ----------
extern "C" void kernel_launch(void* const* d_in, const int* in_sizes, int n_in,
                              void* d_out, int out_size, void* d_ws, size_t ws_size,
                              hipStream_t stream) {
    const float* x    = (const float*)d_in[0];
    const int*   ei   = (const int*)d_in[1];
    const float* W    = (const float*)d_in[2];
    const float* b    = (const float*)d_in[3];
    const float* w_mu = (const float*)d_in[4];
    const float* b_mu = (const float*)d_in[5];
    const float* w_ls = (const float*)d_in[6];
    const float* b_ls = (const float*)d_in[7];

    const int N = N_NODES, E = N_EDGES;
    const int NB = (N + 255) / 256;
    char* p = (char*)d_ws;
    auto alloc = [&](size_t bytes) {
        char* r = p;
        p += (bytes + 511) & ~(size_t)511;
        return r;
    };
    float*  deg    = (float*)alloc((size_t)N * 4);
    int*    indeg  = (int*)alloc((size_t)N * 4);
    int*    rowptr = (int*)alloc((size_t)(N + 1) * 4);
    int*    cursor = (int*)alloc((size_t)N * 4);
    int*    loc    = (int*)alloc((size_t)N * 4);
    int*    bsum   = (int*)alloc((size_t)(NB + 1) * 4);
    int*    col    = (int*)alloc((size_t)E * 4);
    float*  ew     = (float*)alloc((size_t)E * 4);
    ushort* WT     = (ushort*)alloc((size_t)K_ORD * CH * CH * 2);
    float*  accbuf = (float*)alloc((size_t)N * CH * 4);

    size_t used = (size_t)(p - (char*)d_ws);
    bool bigpath = ws_size >= used + (size_t)K_ORD * SLICE * 2 + (1u << 20);

    hipMemsetAsync(deg, 0, (size_t)N * 4, stream);
    hipMemsetAsync(indeg, 0, (size_t)N * 4, stream);

    count_kernel<<<(E + 255) / 256, 256, 0, stream>>>(ei, deg, indeg, E);
    scan1_kernel<<<NB, 256, 0, stream>>>(indeg, loc, bsum, N);
    scan2_kernel<<<1, 256, 0, stream>>>(bsum, NB);
    scan3_kernel<<<NB, 256, 0, stream>>>(loc, bsum, rowptr, cursor, N, NB);
    scatter_kernel<<<(E + 255) / 256, 256, 0, stream>>>(ei, deg, cursor, col, ew, E);
    wprep_kernel<<<(K_ORD * 128 * 32 + 255) / 256, 256, 0, stream>>>(W, WT);

    int gemm_grid = (N + 127) / 128;
    int prop_grid = (N + 3) / 4;
    int cvt_grid = (N * 16 + 255) / 256;

    if (bigpath) {
        ushort* T = (ushort*)alloc((size_t)K_ORD * SLICE * 2);  // [K][2][N][64] fp16
        // T0 = fp16(x)
        cvt_kernel<<<cvt_grid, 256, 0, stream>>>(x, T, N * 16);
        // all k for half 0, then all k for half 1 (channels fully independent)
        for (int h = 0; h < 2; ++h) {
            ushort* Th = T + (size_t)h * HS;
            prop_kernel<<<prop_grid, 256, 0, stream>>>(Th, Th, Th + 2 * HS,
                                                       rowptr, col, ew, N, 0);
            for (int k = 2; k < K_ORD; ++k)
                prop_kernel<<<prop_grid, 256, 0, stream>>>(
                    Th + (size_t)(k - 1) * 2 * HS, Th + (size_t)(k - 2) * 2 * HS,
                    Th + (size_t)k * 2 * HS, rowptr, col, ew, N, 1);
        }
        // acc = sum_k T_k @ W_k  (single K=3200 GEMM)
        gemm_kernel<<<gemm_grid, 256, 0, stream>>>(T, 2 * HS, WT, accbuf, N, 0, K_ORD, 0);
    } else {
        ushort* r0 = (ushort*)alloc(SLICE * 2);
        ushort* r1 = (ushort*)alloc(SLICE * 2);
        ushort* r2 = (ushort*)alloc(SLICE * 2);
        ushort* Ss[3] = { r0, r1, r2 };
        cvt_kernel<<<cvt_grid, 256, 0, stream>>>(x, r0, N * 16);
        gemm_kernel<<<gemm_grid, 256, 0, stream>>>(r0, 0, WT, accbuf, N, 0, 1, 0);
        for (int h = 0; h < 2; ++h)
            prop_kernel<<<prop_grid, 256, 0, stream>>>(r0 + (size_t)h * HS,
                                                       r0 + (size_t)h * HS,
                                                       r1 + (size_t)h * HS,
                                                       rowptr, col, ew, N, 0);
        gemm_kernel<<<gemm_grid, 256, 0, stream>>>(r1, 0, WT, accbuf, N, 1, 1, 1);
        for (int k = 2; k < K_ORD; ++k) {
            for (int h = 0; h < 2; ++h)
                prop_kernel<<<prop_grid, 256, 0, stream>>>(
                    Ss[(k - 1) % 3] + (size_t)h * HS, Ss[(k - 2) % 3] + (size_t)h * HS,
                    Ss[k % 3] + (size_t)h * HS, rowptr, col, ew, N, 1);
            gemm_kernel<<<gemm_grid, 256, 0, stream>>>(Ss[k % 3], 0, WT, accbuf, N, k, 1, 1);
        }
    }

    head_kernel<<<gemm_grid, 256, 0, stream>>>(accbuf, b, w_mu, b_mu, w_ls, b_ls,
                                               (float*)d_out, N);
}